// Round 1
// baseline (378.454 us; speedup 1.0000x reference)
//
#include <hip/hip_runtime.h>
#include <math.h>

#define N_NODES 60000
#define N_EDGES 240000
#define F_INQ 10
#define G_DIM 512

__device__ __forceinline__ void atomic_add_f32(float* addr, float v) {
    unsafeAtomicAdd(addr, v);
}

// ---------------------------------------------------------------------------
// K1: per-node transform 1. Packs per node (96 floats):
//   [ xW_gcn1(16) | z1_s0(16) | z1_s1(16) | z1_s2(16) | z1_bias(16) | root1+bias1(16) ]
// slot = j>>4 maps to weight matrix: 0=W_gcn1, 1..3=We1[s], 4=be1-mat, 5=root1.
// LDS slot stride 168 (=160+8) avoids bank conflicts.
// ---------------------------------------------------------------------------
__global__ __launch_bounds__(256) void k1_node1(
    const float* __restrict__ x,
    const float* __restrict__ Wg1,   // [10,16]
    const float* __restrict__ We1,   // [3,160]
    const float* __restrict__ be1,   // [160]
    const float* __restrict__ root1, // [160]
    const float* __restrict__ bias1, // [16]
    float* __restrict__ A)           // [N,96]
{
    __shared__ float w[6 * 168 + 16];
    for (int t = threadIdx.x; t < 6 * 168 + 16; t += 256) {
        float v = 0.f;
        if (t >= 6 * 168) v = bias1[t - 6 * 168];
        else {
            int slot = t / 168, r = t - slot * 168;
            if (r < 160) {
                if (slot == 0)      v = Wg1[r];
                else if (slot <= 3) v = We1[(slot - 1) * 160 + r];
                else if (slot == 4) v = be1[r];
                else                v = root1[r];
            }
        }
        w[t] = v;
    }
    __syncthreads();
    int idx = blockIdx.x * 256 + threadIdx.x;
    if (idx >= N_NODES * 96) return;
    int node = idx / 96;
    int j = idx - node * 96;
    int slot = j >> 4, o = j & 15;
    const float* xp = x + node * F_INQ;
    const float* wp = w + slot * 168 + o;
    float acc = (slot == 5) ? w[6 * 168 + o] : 0.f;
#pragma unroll
    for (int f = 0; f < F_INQ; ++f)
        acc += xp[f] * wp[f * 16];
    A[idx] = acc;
}

// ---------------------------------------------------------------------------
// K3: edge scatter layer 1. Thread per (edge, o<16).
// msg_gcn = a * xW[col,o];  msg_ecc = zb[col,o] + sum_s e_s * z_s[col,o]
// ---------------------------------------------------------------------------
__global__ __launch_bounds__(256) void k3_edge1(
    const float* __restrict__ A,
    const int* __restrict__ ei,      // [2,E]
    const float* __restrict__ a_vals,
    const float* __restrict__ efeat, // [E,3]
    float* __restrict__ g1acc, float* __restrict__ c1acc)
{
    int idx = blockIdx.x * 256 + threadIdx.x;
    int e = idx >> 4, o = idx & 15;
    if (e >= N_EDGES) return;
    int row = ei[e], col = ei[N_EDGES + e];
    float a  = a_vals[e];
    float e0 = efeat[e * 3 + 0], e1 = efeat[e * 3 + 1], e2 = efeat[e * 3 + 2];
    const float* Ac = A + col * 96;
    float xw    = Ac[o];
    float msg_c = Ac[64 + o] + e0 * Ac[16 + o] + e1 * Ac[32 + o] + e2 * Ac[48 + o];
    atomic_add_f32(&g1acc[row * 16 + o], a * xw);
    atomic_add_f32(&c1acc[row * 16 + o], msg_c);
}

// ---------------------------------------------------------------------------
// K4a: finalize layer 1 in place: g1 = relu(g1acc+b), c1 = relu(c1acc + r1)
// ---------------------------------------------------------------------------
__global__ __launch_bounds__(256) void k4a_finalize1(
    const float* __restrict__ A,
    const float* __restrict__ b_gcn1,
    float* __restrict__ g1acc, float* __restrict__ c1acc)
{
    int idx = blockIdx.x * 256 + threadIdx.x;
    if (idx >= N_NODES * 16) return;
    int node = idx >> 4, f = idx & 15;
    float g = g1acc[idx] + b_gcn1[f];
    g1acc[idx] = g > 0.f ? g : 0.f;
    float c = c1acc[idx] + A[node * 96 + 80 + f];
    c1acc[idx] = c > 0.f ? c : 0.f;
}

// ---------------------------------------------------------------------------
// K4b: per-node transform 2. Packs per node (192 floats):
//   [ g1@W_gcn2(32) | z2_s0(32) | z2_s1(32) | z2_s2(32) | z2_bias(32) | root2+bias2(32) ]
// slot = j>>5: 0 uses g1, 1..5 use c1. LDS slot stride 520 (=512+8).
// Overwrites the A region (A is dead after K4a).
// ---------------------------------------------------------------------------
__global__ __launch_bounds__(256) void k4b_node2(
    const float* __restrict__ g1,
    const float* __restrict__ c1,
    const float* __restrict__ Wg2,   // [16,32]
    const float* __restrict__ We2,   // [3,512]
    const float* __restrict__ be2,   // [512]
    const float* __restrict__ root2, // [512]
    const float* __restrict__ bias2, // [32]
    float* __restrict__ B)           // [N,192]
{
    __shared__ float w[6 * 520 + 32];
    for (int t = threadIdx.x; t < 6 * 520 + 32; t += 256) {
        float v = 0.f;
        if (t >= 6 * 520) v = bias2[t - 6 * 520];
        else {
            int slot = t / 520, r = t - slot * 520;
            if (r < 512) {
                if (slot == 0)      v = Wg2[r];
                else if (slot <= 3) v = We2[(slot - 1) * 512 + r];
                else if (slot == 4) v = be2[r];
                else                v = root2[r];
            }
        }
        w[t] = v;
    }
    __syncthreads();
    int idx = blockIdx.x * 256 + threadIdx.x;
    if (idx >= N_NODES * 192) return;
    int node = idx / 192;
    int j = idx - node * 192;
    int slot = j >> 5, o = j & 31;
    const float* in = (slot == 0 ? g1 : c1) + node * 16;
    const float* wp = w + slot * 520 + o;
    float acc = (slot == 5) ? w[6 * 520 + o] : 0.f;
#pragma unroll
    for (int f = 0; f < 16; ++f)
        acc += in[f] * wp[f * 32];
    B[idx] = acc;
}

// ---------------------------------------------------------------------------
// K6: edge scatter layer 2. Thread per (edge, o<32).
// ---------------------------------------------------------------------------
__global__ __launch_bounds__(256) void k6_edge2(
    const float* __restrict__ B,
    const int* __restrict__ ei,
    const float* __restrict__ a_vals,
    const float* __restrict__ efeat,
    float* __restrict__ g2acc, float* __restrict__ c2acc)
{
    int idx = blockIdx.x * 256 + threadIdx.x;
    int e = idx >> 5, o = idx & 31;
    if (e >= N_EDGES) return;
    int row = ei[e], col = ei[N_EDGES + e];
    float a  = a_vals[e];
    float e0 = efeat[e * 3 + 0], e1 = efeat[e * 3 + 1], e2 = efeat[e * 3 + 2];
    const float* Bc = B + col * 192;
    float xw    = Bc[o];
    float msg_c = Bc[128 + o] + e0 * Bc[32 + o] + e1 * Bc[64 + o] + e2 * Bc[96 + o];
    atomic_add_f32(&g2acc[row * 32 + o], a * xw);
    atomic_add_f32(&c2acc[row * 32 + o], msg_c);
}

// ---------------------------------------------------------------------------
// K7: finalize layer 2 + global sum pool into p[G,64]. Thread per (node, j<64).
// j<32: gcn branch (p[:, :32]); j>=32: ecc branch (p[:, 32:]).
// ---------------------------------------------------------------------------
__global__ __launch_bounds__(256) void k7_pool(
    const float* __restrict__ g2acc, const float* __restrict__ c2acc,
    const float* __restrict__ B,     // r2 at [node*192 + 160 + o]
    const float* __restrict__ b_gcn2,
    const int* __restrict__ seg,
    float* __restrict__ p)
{
    int idx = blockIdx.x * 256 + threadIdx.x;
    if (idx >= N_NODES * 64) return;
    int node = idx >> 6, j = idx & 63;
    float v;
    if (j < 32) {
        v = g2acc[node * 32 + j] + b_gcn2[j];
    } else {
        int o = j - 32;
        v = c2acc[node * 32 + o] + B[node * 192 + 160 + o];
    }
    v = v > 0.f ? v : 0.f;
    atomic_add_f32(&p[seg[node] * 64 + j], v);
}

// ---------------------------------------------------------------------------
// K8: MLP head, one thread per graph. 64 -> 16 -> 8 -> sigmoid(1).
// ---------------------------------------------------------------------------
__global__ __launch_bounds__(256) void k8_head(
    const float* __restrict__ p,
    const float* __restrict__ Wd1, const float* __restrict__ bd1,
    const float* __restrict__ Wd2, const float* __restrict__ bd2,
    const float* __restrict__ Wo,  const float* __restrict__ bo,
    float* __restrict__ out)
{
    __shared__ float w1[64 * 16], b1[16], w2[16 * 8], b2[8], wo[8], bos;
    for (int t = threadIdx.x; t < 1024; t += 256) w1[t] = Wd1[t];
    if (threadIdx.x < 128) w2[threadIdx.x] = Wd2[threadIdx.x];
    if (threadIdx.x < 16)  b1[threadIdx.x] = bd1[threadIdx.x];
    if (threadIdx.x < 8) { b2[threadIdx.x] = bd2[threadIdx.x]; wo[threadIdx.x] = Wo[threadIdx.x]; }
    if (threadIdx.x == 0)  bos = bo[0];
    __syncthreads();
    int g = blockIdx.x * 256 + threadIdx.x;
    if (g >= G_DIM) return;
    float pl[64];
#pragma unroll
    for (int k = 0; k < 64; ++k) pl[k] = p[g * 64 + k];
    float h1[16];
#pragma unroll
    for (int i = 0; i < 16; ++i) {
        float acc = b1[i];
#pragma unroll
        for (int k = 0; k < 64; ++k) acc += pl[k] * w1[k * 16 + i];
        h1[i] = acc > 0.f ? acc : 0.f;
    }
    float h2[8];
#pragma unroll
    for (int i = 0; i < 8; ++i) {
        float acc = b2[i];
#pragma unroll
        for (int k = 0; k < 16; ++k) acc += h1[k] * w2[k * 8 + i];
        h2[i] = acc > 0.f ? acc : 0.f;
    }
    float t = bos;
#pragma unroll
    for (int k = 0; k < 8; ++k) t += h2[k] * wo[k];
    out[g] = 1.f / (1.f + expf(-t));
}

// ---------------------------------------------------------------------------
// Workspace layout (floats), total N*288 + G*64 = 17,312,768 floats (~69 MB):
//   [0, N*192)        : A (N*96, layer-1 packed) overlaid later by B (N*192)
//   [N*192, N*208)    : g1acc / g1
//   [N*208, N*224)    : c1acc / c1
//   [N*224, N*256)    : g2acc
//   [N*256, N*288)    : c2acc
//   [N*288, +G*64)    : p
// ---------------------------------------------------------------------------
extern "C" void kernel_launch(void* const* d_in, const int* in_sizes, int n_in,
                              void* d_out, int out_size, void* d_ws, size_t ws_size,
                              hipStream_t stream)
{
    const float* x      = (const float*)d_in[0];
    const float* a_vals = (const float*)d_in[1];
    const float* efeat  = (const float*)d_in[2];
    const int*   ei     = (const int*)d_in[3];
    const int*   seg    = (const int*)d_in[4];
    const float* Wg1    = (const float*)d_in[5];
    const float* bg1    = (const float*)d_in[6];
    const float* Wg2    = (const float*)d_in[7];
    const float* bg2    = (const float*)d_in[8];
    const float* We1    = (const float*)d_in[9];
    const float* be1    = (const float*)d_in[10];
    const float* root1  = (const float*)d_in[11];
    const float* bias1  = (const float*)d_in[12];
    const float* We2    = (const float*)d_in[13];
    const float* be2    = (const float*)d_in[14];
    const float* root2  = (const float*)d_in[15];
    const float* bias2  = (const float*)d_in[16];
    const float* Wd1    = (const float*)d_in[17];
    const float* bd1    = (const float*)d_in[18];
    const float* Wd2    = (const float*)d_in[19];
    const float* bd2    = (const float*)d_in[20];
    const float* Wo     = (const float*)d_in[21];
    const float* bo     = (const float*)d_in[22];

    float* ws    = (float*)d_ws;
    float* A     = ws;
    float* B     = ws;
    float* g1acc = ws + (size_t)N_NODES * 192;
    float* c1acc = g1acc + (size_t)N_NODES * 16;
    float* g2acc = c1acc + (size_t)N_NODES * 16;
    float* c2acc = g2acc + (size_t)N_NODES * 32;
    float* p     = c2acc + (size_t)N_NODES * 32;
    float* out   = (float*)d_out;

    hipMemsetAsync(g1acc, 0, sizeof(float) * N_NODES * 32, stream); // g1acc+c1acc
    hipMemsetAsync(g2acc, 0, sizeof(float) * N_NODES * 64, stream); // g2acc+c2acc
    hipMemsetAsync(p,     0, sizeof(float) * G_DIM * 64,   stream);

    k1_node1<<<N_NODES * 96 / 256, 256, 0, stream>>>(x, Wg1, We1, be1, root1, bias1, A);
    k3_edge1<<<N_EDGES * 16 / 256, 256, 0, stream>>>(A, ei, a_vals, efeat, g1acc, c1acc);
    k4a_finalize1<<<N_NODES * 16 / 256, 256, 0, stream>>>(A, bg1, g1acc, c1acc);
    k4b_node2<<<N_NODES * 192 / 256, 256, 0, stream>>>(g1acc, c1acc, Wg2, We2, be2, root2, bias2, B);
    k6_edge2<<<N_EDGES * 32 / 256, 256, 0, stream>>>(B, ei, a_vals, efeat, g2acc, c2acc);
    k7_pool<<<N_NODES * 64 / 256, 256, 0, stream>>>(g2acc, c2acc, B, bg2, seg, p);
    k8_head<<<2, 256, 0, stream>>>(p, Wd1, bd1, Wd2, bd2, Wo, bo, out);
}

// Round 2
// 267.590 us; speedup vs baseline: 1.4143x; 1.4143x over previous
//
#include <hip/hip_runtime.h>
#include <math.h>

#define N_NODES 60000
#define N_EDGES 240000
#define F_INQ 10
#define G_DIM 512

__device__ __forceinline__ void atomic_add_f32(float* addr, float v) {
    unsafeAtomicAdd(addr, v);
}

// ---------------------------------------------------------------------------
// K1: per-node transform 1 (grid-stride, weights staged once per block).
// Packs per node (96 floats):
//   [ xW_gcn1(16) | z1_s0(16) | z1_s1(16) | z1_s2(16) | z1_bias(16) | root1+bias1(16) ]
// slot = j>>4: 0=W_gcn1, 1..3=We1[s], 4=be1-mat, 5=root1. LDS stride 168=160+8.
// ---------------------------------------------------------------------------
__global__ __launch_bounds__(256) void k1_node1(
    const float* __restrict__ x,
    const float* __restrict__ Wg1,   // [10,16]
    const float* __restrict__ We1,   // [3,160]
    const float* __restrict__ be1,   // [160]
    const float* __restrict__ root1, // [160]
    const float* __restrict__ bias1, // [16]
    float* __restrict__ A)           // [N,96]
{
    __shared__ float w[6 * 168 + 16];
    for (int t = threadIdx.x; t < 6 * 168 + 16; t += 256) {
        float v = 0.f;
        if (t >= 6 * 168) v = bias1[t - 6 * 168];
        else {
            int slot = t / 168, r = t - slot * 168;
            if (r < 160) {
                if (slot == 0)      v = Wg1[r];
                else if (slot <= 3) v = We1[(slot - 1) * 160 + r];
                else if (slot == 4) v = be1[r];
                else                v = root1[r];
            }
        }
        w[t] = v;
    }
    __syncthreads();
    const int total = N_NODES * 96;
    const int stride = gridDim.x * 256;
    for (int idx = blockIdx.x * 256 + threadIdx.x; idx < total; idx += stride) {
        int node = idx / 96;
        int j = idx - node * 96;
        int slot = j >> 4, o = j & 15;
        const float* xp = x + node * F_INQ;
        const float* wp = w + slot * 168 + o;
        float acc = (slot == 5) ? w[6 * 168 + o] : 0.f;
#pragma unroll
        for (int f = 0; f < F_INQ; ++f)
            acc += xp[f] * wp[f * 16];
        A[idx] = acc;
    }
}

// ---------------------------------------------------------------------------
// K3: edge scatter layer 1. Thread per (edge, o<16).
// ---------------------------------------------------------------------------
__global__ __launch_bounds__(256) void k3_edge1(
    const float* __restrict__ A,
    const int* __restrict__ ei,      // [2,E]
    const float* __restrict__ a_vals,
    const float* __restrict__ efeat, // [E,3]
    float* __restrict__ g1acc, float* __restrict__ c1acc)
{
    int idx = blockIdx.x * 256 + threadIdx.x;
    int e = idx >> 4, o = idx & 15;
    if (e >= N_EDGES) return;
    int row = ei[e], col = ei[N_EDGES + e];
    float a  = a_vals[e];
    float e0 = efeat[e * 3 + 0], e1 = efeat[e * 3 + 1], e2 = efeat[e * 3 + 2];
    const float* Ac = A + col * 96;
    float xw    = Ac[o];
    float msg_c = Ac[64 + o] + e0 * Ac[16 + o] + e1 * Ac[32 + o] + e2 * Ac[48 + o];
    atomic_add_f32(&g1acc[row * 16 + o], a * xw);
    atomic_add_f32(&c1acc[row * 16 + o], msg_c);
}

// ---------------------------------------------------------------------------
// K4a: finalize layer 1 in place.
// ---------------------------------------------------------------------------
__global__ __launch_bounds__(256) void k4a_finalize1(
    const float* __restrict__ A,
    const float* __restrict__ b_gcn1,
    float* __restrict__ g1acc, float* __restrict__ c1acc)
{
    int idx = blockIdx.x * 256 + threadIdx.x;
    if (idx >= N_NODES * 16) return;
    int node = idx >> 4, f = idx & 15;
    float g = g1acc[idx] + b_gcn1[f];
    g1acc[idx] = g > 0.f ? g : 0.f;
    float c = c1acc[idx] + A[node * 96 + 80 + f];
    c1acc[idx] = c > 0.f ? c : 0.f;
}

// ---------------------------------------------------------------------------
// K4b: per-node transform 2 (grid-stride, weights staged once per block;
// float4 input loads). Packs per node (192 floats):
//   [ g1@W_gcn2(32) | z2_s0(32) | z2_s1(32) | z2_s2(32) | z2_bias(32) | root2+bias2(32) ]
// slot = j>>5: 0 uses g1, 1..5 use c1. LDS slot stride 520=512+8
// (banks: (slot*8 + o) % 32 -> 2-way alias per wave = free).
// ---------------------------------------------------------------------------
__global__ __launch_bounds__(256) void k4b_node2(
    const float* __restrict__ g1,
    const float* __restrict__ c1,
    const float* __restrict__ Wg2,   // [16,32]
    const float* __restrict__ We2,   // [3,512]
    const float* __restrict__ be2,   // [512]
    const float* __restrict__ root2, // [512]
    const float* __restrict__ bias2, // [32]
    float* __restrict__ B)           // [N,192]
{
    __shared__ float w[6 * 520 + 32];
    for (int t = threadIdx.x; t < 6 * 520 + 32; t += 256) {
        float v = 0.f;
        if (t >= 6 * 520) v = bias2[t - 6 * 520];
        else {
            int slot = t / 520, r = t - slot * 520;
            if (r < 512) {
                if (slot == 0)      v = Wg2[r];
                else if (slot <= 3) v = We2[(slot - 1) * 512 + r];
                else if (slot == 4) v = be2[r];
                else                v = root2[r];
            }
        }
        w[t] = v;
    }
    __syncthreads();
    const int total = N_NODES * 192;
    const int stride = gridDim.x * 256;
    for (int idx = blockIdx.x * 256 + threadIdx.x; idx < total; idx += stride) {
        int node = idx / 192;
        int j = idx - node * 192;
        int slot = j >> 5, o = j & 31;
        const float* in = (slot == 0 ? g1 : c1) + node * 16;
        const float4* inv = reinterpret_cast<const float4*>(in);
        float4 i0 = inv[0], i1 = inv[1], i2 = inv[2], i3 = inv[3];
        const float* wp = w + slot * 520 + o;
        float acc = (slot == 5) ? w[6 * 520 + o] : 0.f;
        acc += i0.x * wp[0 * 32] + i0.y * wp[1 * 32] + i0.z * wp[2 * 32] + i0.w * wp[3 * 32];
        acc += i1.x * wp[4 * 32] + i1.y * wp[5 * 32] + i1.z * wp[6 * 32] + i1.w * wp[7 * 32];
        acc += i2.x * wp[8 * 32] + i2.y * wp[9 * 32] + i2.z * wp[10 * 32] + i2.w * wp[11 * 32];
        acc += i3.x * wp[12 * 32] + i3.y * wp[13 * 32] + i3.z * wp[14 * 32] + i3.w * wp[15 * 32];
        B[idx] = acc;
    }
}

// ---------------------------------------------------------------------------
// K6: edge scatter layer 2. Thread per (edge, o<32).
// ---------------------------------------------------------------------------
__global__ __launch_bounds__(256) void k6_edge2(
    const float* __restrict__ B,
    const int* __restrict__ ei,
    const float* __restrict__ a_vals,
    const float* __restrict__ efeat,
    float* __restrict__ g2acc, float* __restrict__ c2acc)
{
    int idx = blockIdx.x * 256 + threadIdx.x;
    int e = idx >> 5, o = idx & 31;
    if (e >= N_EDGES) return;
    int row = ei[e], col = ei[N_EDGES + e];
    float a  = a_vals[e];
    float e0 = efeat[e * 3 + 0], e1 = efeat[e * 3 + 1], e2 = efeat[e * 3 + 2];
    const float* Bc = B + col * 192;
    float xw    = Bc[o];
    float msg_c = Bc[128 + o] + e0 * Bc[32 + o] + e1 * Bc[64 + o] + e2 * Bc[96 + o];
    atomic_add_f32(&g2acc[row * 32 + o], a * xw);
    atomic_add_f32(&c2acc[row * 32 + o], msg_c);
}

// ---------------------------------------------------------------------------
// K7: finalize layer 2 + global sum pool into p[G,64]. Thread per (node, j<64).
// ---------------------------------------------------------------------------
__global__ __launch_bounds__(256) void k7_pool(
    const float* __restrict__ g2acc, const float* __restrict__ c2acc,
    const float* __restrict__ B,     // r2 at [node*192 + 160 + o]
    const float* __restrict__ b_gcn2,
    const int* __restrict__ seg,
    float* __restrict__ p)
{
    int idx = blockIdx.x * 256 + threadIdx.x;
    if (idx >= N_NODES * 64) return;
    int node = idx >> 6, j = idx & 63;
    float v;
    if (j < 32) {
        v = g2acc[node * 32 + j] + b_gcn2[j];
    } else {
        int o = j - 32;
        v = c2acc[node * 32 + o] + B[node * 192 + 160 + o];
    }
    v = v > 0.f ? v : 0.f;
    atomic_add_f32(&p[seg[node] * 64 + j], v);
}

// ---------------------------------------------------------------------------
// K8: MLP head, one thread per graph. 64 -> 16 -> 8 -> sigmoid(1).
// ---------------------------------------------------------------------------
__global__ __launch_bounds__(256) void k8_head(
    const float* __restrict__ p,
    const float* __restrict__ Wd1, const float* __restrict__ bd1,
    const float* __restrict__ Wd2, const float* __restrict__ bd2,
    const float* __restrict__ Wo,  const float* __restrict__ bo,
    float* __restrict__ out)
{
    __shared__ float w1[64 * 16], b1[16], w2[16 * 8], b2[8], wo[8], bos;
    for (int t = threadIdx.x; t < 1024; t += 256) w1[t] = Wd1[t];
    if (threadIdx.x < 128) w2[threadIdx.x] = Wd2[threadIdx.x];
    if (threadIdx.x < 16)  b1[threadIdx.x] = bd1[threadIdx.x];
    if (threadIdx.x < 8) { b2[threadIdx.x] = bd2[threadIdx.x]; wo[threadIdx.x] = Wo[threadIdx.x]; }
    if (threadIdx.x == 0)  bos = bo[0];
    __syncthreads();
    int g = blockIdx.x * 256 + threadIdx.x;
    if (g >= G_DIM) return;
    float pl[64];
#pragma unroll
    for (int k = 0; k < 64; ++k) pl[k] = p[g * 64 + k];
    float h1[16];
#pragma unroll
    for (int i = 0; i < 16; ++i) {
        float acc = b1[i];
#pragma unroll
        for (int k = 0; k < 64; ++k) acc += pl[k] * w1[k * 16 + i];
        h1[i] = acc > 0.f ? acc : 0.f;
    }
    float h2[8];
#pragma unroll
    for (int i = 0; i < 8; ++i) {
        float acc = b2[i];
#pragma unroll
        for (int k = 0; k < 16; ++k) acc += h1[k] * w2[k * 8 + i];
        h2[i] = acc > 0.f ? acc : 0.f;
    }
    float t = bos;
#pragma unroll
    for (int k = 0; k < 8; ++k) t += h2[k] * wo[k];
    out[g] = 1.f / (1.f + expf(-t));
}

// ---------------------------------------------------------------------------
// Workspace layout (floats), total N*288 + G*64 floats (~69 MB):
//   [0, N*192)        : A (N*96) overlaid later by B (N*192)
//   [N*192, N*208)    : g1acc / g1
//   [N*208, N*224)    : c1acc / c1
//   [N*224, N*256)    : g2acc
//   [N*256, N*288)    : c2acc
//   [N*288, +G*64)    : p
// ---------------------------------------------------------------------------
extern "C" void kernel_launch(void* const* d_in, const int* in_sizes, int n_in,
                              void* d_out, int out_size, void* d_ws, size_t ws_size,
                              hipStream_t stream)
{
    const float* x      = (const float*)d_in[0];
    const float* a_vals = (const float*)d_in[1];
    const float* efeat  = (const float*)d_in[2];
    const int*   ei     = (const int*)d_in[3];
    const int*   seg    = (const int*)d_in[4];
    const float* Wg1    = (const float*)d_in[5];
    const float* bg1    = (const float*)d_in[6];
    const float* Wg2    = (const float*)d_in[7];
    const float* bg2    = (const float*)d_in[8];
    const float* We1    = (const float*)d_in[9];
    const float* be1    = (const float*)d_in[10];
    const float* root1  = (const float*)d_in[11];
    const float* bias1  = (const float*)d_in[12];
    const float* We2    = (const float*)d_in[13];
    const float* be2    = (const float*)d_in[14];
    const float* root2  = (const float*)d_in[15];
    const float* bias2  = (const float*)d_in[16];
    const float* Wd1    = (const float*)d_in[17];
    const float* bd1    = (const float*)d_in[18];
    const float* Wd2    = (const float*)d_in[19];
    const float* bd2    = (const float*)d_in[20];
    const float* Wo     = (const float*)d_in[21];
    const float* bo     = (const float*)d_in[22];

    float* ws    = (float*)d_ws;
    float* A     = ws;
    float* B     = ws;
    float* g1acc = ws + (size_t)N_NODES * 192;
    float* c1acc = g1acc + (size_t)N_NODES * 16;
    float* g2acc = c1acc + (size_t)N_NODES * 16;
    float* c2acc = g2acc + (size_t)N_NODES * 32;
    float* p     = c2acc + (size_t)N_NODES * 32;
    float* out   = (float*)d_out;

    hipMemsetAsync(g1acc, 0, sizeof(float) * N_NODES * 32, stream); // g1acc+c1acc
    hipMemsetAsync(g2acc, 0, sizeof(float) * N_NODES * 64, stream); // g2acc+c2acc
    hipMemsetAsync(p,     0, sizeof(float) * G_DIM * 64,   stream);

    // grid-stride kernels: fixed 1280 blocks (5/CU) so LDS weight staging is
    // amortized ~35x vs one-shot mapping (R1's k4b was staging-bound).
    k1_node1<<<1280, 256, 0, stream>>>(x, Wg1, We1, be1, root1, bias1, A);
    k3_edge1<<<N_EDGES * 16 / 256, 256, 0, stream>>>(A, ei, a_vals, efeat, g1acc, c1acc);
    k4a_finalize1<<<N_NODES * 16 / 256, 256, 0, stream>>>(A, bg1, g1acc, c1acc);
    k4b_node2<<<1280, 256, 0, stream>>>(g1acc, c1acc, Wg2, We2, be2, root2, bias2, B);
    k6_edge2<<<N_EDGES * 32 / 256, 256, 0, stream>>>(B, ei, a_vals, efeat, g2acc, c2acc);
    k7_pool<<<N_NODES * 64 / 256, 256, 0, stream>>>(g2acc, c2acc, B, bg2, seg, p);
    k8_head<<<2, 256, 0, stream>>>(p, Wd1, bd1, Wd2, bd2, Wo, bo, out);
}